// Round 1
// 842.730 us; speedup vs baseline: 1.0970x; 1.0970x over previous
//
#include <hip/hip_runtime.h>

typedef __bf16 bf16;
typedef __bf16 bf16x8 __attribute__((ext_vector_type(8)));
typedef __bf16 bf16x4 __attribute__((ext_vector_type(4)));
typedef float  f32x4  __attribute__((ext_vector_type(4)));

#define LDA 264                       // padded row stride (bf16 elems), 528 B
#define LDS_ELEMS (2 * 64 * LDA)      // X0 (Xs, later O) + X1 (Xq) = 67,584 B

static __device__ __forceinline__ f32x4 mfma16(bf16x8 a, bf16x8 b, f32x4 c) {
  return __builtin_amdgcn_mfma_f32_16x16x32_bf16(a, b, c, 0, 0, 0);
}

static __device__ __forceinline__ unsigned pk2(float x, float y) {
  union { bf16 h; unsigned short u; } a, b;
  a.h = (bf16)x; b.h = (bf16)y;
  return (unsigned)a.u | ((unsigned)b.u << 16);
}

// In-register D-layout -> MFMA-fragment redistribution (q-axis only).
// Source: lane (c,q) holds in t0[r] (m=0) / t1[r] (m=1) the element with
// inner index 16m+4q+r; outer index = c (unchanged by this transform).
// Target: bf16x8 where lane (c,q') elem j holds inner index 8q'+j.
//   element (inner=8q'+j): m = q'>>1, q_src = 2*(q'&1) + (j>>2), r = j&3.
// srcA = c + 32*(q'&1)  (lane of q_src for j=0..3; +16 gives j=4..7),
// hi   = q'>>1          (selects m tile). Both precomputed per lane.
static __device__ __forceinline__ bf16x8 redist(f32x4 t0, f32x4 t1,
                                                int srcA, bool hi) {
  unsigned p0 = pk2(t0[0], t0[1]);
  unsigned p1 = pk2(t0[2], t0[3]);
  unsigned p2 = pk2(t1[0], t1[1]);
  unsigned p3 = pk2(t1[2], t1[3]);
  int srcB = srcA + 16;
  unsigned a0 = __shfl(p0, srcA), a1 = __shfl(p1, srcA);
  unsigned a2 = __shfl(p2, srcA), a3 = __shfl(p3, srcA);
  unsigned b0 = __shfl(p0, srcB), b1 = __shfl(p1, srcB);
  unsigned b2 = __shfl(p2, srcB), b3 = __shfl(p3, srcB);
  union { unsigned u[4]; bf16x8 v; } r;
  r.u[0] = hi ? a2 : a0;
  r.u[1] = hi ? a3 : a1;
  r.u[2] = hi ? b2 : b0;
  r.u[3] = hi ? b3 : b1;
  return r.v;
}

// Prep: f32 weights -> transposed bf16 ([n_out][k], k-contiguous). Wq is
// pre-scaled by 1/sqrt(d). biasT is [h][query][key] f32 so the swapped-QK^T
// accumulator (rows = keys) inits with one dwordx4 per tile.
__global__ void prep_kernel(const float* __restrict__ Wq, const float* __restrict__ Wkv,
                            const float* __restrict__ Wp, const float* __restrict__ btab,
                            bf16* __restrict__ WqT, bf16* __restrict__ WkvT,
                            bf16* __restrict__ WpT, float* __restrict__ biasT) {
  int idx = blockIdx.x * 512 + threadIdx.x;       // 0 .. 294911
  if (idx < 65536) {
    int n = idx >> 8, k = idx & 255;
    WqT[idx] = (bf16)(Wq[k * 256 + n] * 0.17677669529663687f);
  } else if (idx < 196608) {
    int j = idx - 65536, n = j >> 8, k = j & 255;
    WkvT[j] = (bf16)Wkv[k * 512 + n];
  } else if (idx < 262144) {
    int j = idx - 196608, n = j >> 8, k = j & 255;
    WpT[j] = (bf16)Wp[k * 256 + n];
  } else {
    int j = idx - 262144;                          // j = h*4096 + rq*64 + ck
    int h = j >> 12, rq = (j >> 6) & 63, ck = j & 63;
    int rel = ((rq >> 3) - (ck >> 3) + 7) * 15 + ((rq & 7) - (ck & 7) + 7);
    biasT[j] = btab[rel * 8 + h];
  }
}

// One workgroup = one 64-token window. 8 waves; wave w owns head w:
// projection columns [32w,32w+32) of Q/K (and V cols 256+[32w,32w+32)).
// Q/K/V/P never touch LDS: producer MFMAs are oriented so the consumer
// fragment's outer index lives in lane bits 0-3, and the k-axis is
// redistributed with q-group shuffles (redist above). LDS holds only the
// shared X tiles (67.6 KB) -> 2 blocks/CU.
__global__ __launch_bounds__(512, 4) void fused_kernel(
    const float* __restrict__ Xq_g, const float* __restrict__ Xs_g,
    const float* __restrict__ bq,  const float* __restrict__ bkv,
    const float* __restrict__ bp,
    const bf16* __restrict__ WqT, const bf16* __restrict__ WkvT,
    const bf16* __restrict__ WpT, const float* __restrict__ biasT,
    float* __restrict__ out) {
  __shared__ __attribute__((aligned(16))) bf16 sm[LDS_ELEMS];
  const int tid  = (int)threadIdx.x;
  const int w    = tid >> 6;        // wave id 0..7 == head
  const int lane = tid & 63;
  const int c    = lane & 15;       // MFMA outer-index lane
  const int q    = lane >> 4;       // MFMA quad
  const int srcA = c + ((q & 1) << 5);   // redist source lane (j=0..3)
  const bool hi  = (q >> 1) != 0;        // redist m-tile select
  bf16* X0 = sm;                    // [64][264] Xs, later O
  bf16* X1 = sm + 64 * LDA;         // [64][264] Xq
  const long long xoff = (long long)blockIdx.x * (64 * 256);

  // ---- stage 0: both input tiles staged together (loads co-issued) ----
  {
    const float4* g0 = (const float4*)(Xs_g + xoff);
    const float4* g1 = (const float4*)(Xq_g + xoff);
    float4 v0[8], v1[8];
    #pragma unroll
    for (int i = 0; i < 8; ++i) v0[i] = g0[tid + i * 512];
    #pragma unroll
    for (int i = 0; i < 8; ++i) v1[i] = g1[tid + i * 512];
    #pragma unroll
    for (int i = 0; i < 8; ++i) {
      int chunk = tid + i * 512;                  // 16B f32 chunks
      int row = chunk >> 6, col = (chunk & 63) << 2;
      bf16x4 s0 = {(bf16)v0[i].x, (bf16)v0[i].y, (bf16)v0[i].z, (bf16)v0[i].w};
      bf16x4 s1 = {(bf16)v1[i].x, (bf16)v1[i].y, (bf16)v1[i].z, (bf16)v1[i].w};
      *(bf16x4*)(X0 + row * LDA + col) = s0;
      *(bf16x4*)(X1 + row * LDA + col) = s1;
    }
  }
  __syncthreads();

  bf16x8 ka[4];      // K A-frags: lane (c,q): K[key=16t+c][dim 8q..8q+7]
  bf16x8 vb[2][2];   // V B-frags: vb[d][t]: lane: V[key=32t+8q..][dim=16d+c]
  bf16x8 qb[4];      // Q B-frags: lane (c,q): Q[query=16t+c][dim 8q..]

  // ---- stage 1: KV projection, wave-private head slice ----
  {
    f32x4 ak[2][4];   // K^T = Wk^T @ Xs^T : D[m=dim][n=token]
    f32x4 av[4][2];   // V   = Xs @ Wv      : D[m=token][n=dim]
    #pragma unroll
    for (int m = 0; m < 2; ++m) {
      f32x4 b4 = *(const f32x4*)(bkv + w * 32 + m * 16 + q * 4);
      #pragma unroll
      for (int n = 0; n < 4; ++n) ak[m][n] = b4;
    }
    #pragma unroll
    for (int n = 0; n < 2; ++n) {
      float bv = bkv[256 + w * 32 + n * 16 + c];
      #pragma unroll
      for (int m = 0; m < 4; ++m) av[m][n] = (f32x4){bv, bv, bv, bv};
    }
    #pragma unroll
    for (int kt = 0; kt < 8; ++kt) {
      bf16x8 xf[4], wk[2], wv[2];
      #pragma unroll
      for (int m = 0; m < 4; ++m)
        xf[m] = *(const bf16x8*)(X0 + (m * 16 + c) * LDA + kt * 32 + q * 8);
      #pragma unroll
      for (int m = 0; m < 2; ++m)
        wk[m] = *(const bf16x8*)(WkvT + (w * 32 + m * 16 + c) * 256 + kt * 32 + q * 8);
      #pragma unroll
      for (int n = 0; n < 2; ++n)
        wv[n] = *(const bf16x8*)(WkvT + (256 + w * 32 + n * 16 + c) * 256 + kt * 32 + q * 8);
      #pragma unroll
      for (int m = 0; m < 2; ++m)
        #pragma unroll
        for (int n = 0; n < 4; ++n)
          ak[m][n] = mfma16(wk[m], xf[n], ak[m][n]);
      #pragma unroll
      for (int m = 0; m < 4; ++m)
        #pragma unroll
        for (int n = 0; n < 2; ++n)
          av[m][n] = mfma16(xf[m], wv[n], av[m][n]);
    }
    #pragma unroll
    for (int t = 0; t < 4; ++t) ka[t] = redist(ak[0][t], ak[1][t], srcA, hi);
    #pragma unroll
    for (int n = 0; n < 2; ++n)
      #pragma unroll
      for (int t = 0; t < 2; ++t)
        vb[n][t] = redist(av[2 * t][n], av[2 * t + 1][n], srcA, hi);
  }

  // ---- stage 2: Q projection (swapped; scale folded into WqT) ----
  {
    const float scale = 0.17677669529663687f;
    f32x4 aq[2][4];   // Q^T : D[m=dim][n=token]
    #pragma unroll
    for (int m = 0; m < 2; ++m) {
      f32x4 b4 = *(const f32x4*)(bq + w * 32 + m * 16 + q * 4);
      f32x4 s4 = {b4[0] * scale, b4[1] * scale, b4[2] * scale, b4[3] * scale};
      #pragma unroll
      for (int n = 0; n < 4; ++n) aq[m][n] = s4;
    }
    #pragma unroll
    for (int kt = 0; kt < 8; ++kt) {
      bf16x8 xf[4], wq[2];
      #pragma unroll
      for (int m = 0; m < 4; ++m)
        xf[m] = *(const bf16x8*)(X1 + (m * 16 + c) * LDA + kt * 32 + q * 8);
      #pragma unroll
      for (int m = 0; m < 2; ++m)
        wq[m] = *(const bf16x8*)(WqT + (w * 32 + m * 16 + c) * 256 + kt * 32 + q * 8);
      #pragma unroll
      for (int m = 0; m < 2; ++m)
        #pragma unroll
        for (int n = 0; n < 4; ++n)
          aq[m][n] = mfma16(wq[m], xf[n], aq[m][n]);
    }
    #pragma unroll
    for (int t = 0; t < 4; ++t) qb[t] = redist(aq[0][t], aq[1][t], srcA, hi);
  }
  __syncthreads();   // all X0/X1 reads done; X0 becomes the O buffer

  // ---- stage 3: attention, fully in registers (swapped QK^T) ----
  #pragma unroll
  for (int p = 0; p < 2; ++p) {            // two passes of 32 query cols
    f32x4 s[4][2];                         // D[m=key][n=query]
    #pragma unroll
    for (int m = 0; m < 4; ++m)
      #pragma unroll
      for (int n = 0; n < 2; ++n)
        s[m][n] = *(const f32x4*)(biasT + w * 4096 +
                                  (p * 32 + n * 16 + c) * 64 + m * 16 + q * 4);
    #pragma unroll
    for (int m = 0; m < 4; ++m)
      #pragma unroll
      for (int n = 0; n < 2; ++n)
        s[m][n] = mfma16(ka[m], qb[p * 2 + n], s[m][n]);

    // softmax over keys: 16 in-lane values + q-group butterfly (xor 16,32)
    #pragma unroll
    for (int n = 0; n < 2; ++n) {
      float mx = s[0][n][0];
      #pragma unroll
      for (int m = 0; m < 4; ++m)
        #pragma unroll
        for (int r = 0; r < 4; ++r) mx = fmaxf(mx, s[m][n][r]);
      mx = fmaxf(mx, __shfl_xor(mx, 16));
      mx = fmaxf(mx, __shfl_xor(mx, 32));
      const float L2E = 1.4426950408889634f;
      float mb = mx * L2E;
      float sum = 0.f;
      #pragma unroll
      for (int m = 0; m < 4; ++m)
        #pragma unroll
        for (int r = 0; r < 4; ++r) {
          float t = exp2f(s[m][n][r] * L2E - mb);
          s[m][n][r] = t;
          sum += t;
        }
      sum += __shfl_xor(sum, 16);
      sum += __shfl_xor(sum, 32);
      float rl = __builtin_amdgcn_rcpf(sum);   // sum >= 1, rcp is safe
      #pragma unroll
      for (int m = 0; m < 4; ++m)
        #pragma unroll
        for (int r = 0; r < 4; ++r) s[m][n][r] *= rl;
    }

    // P -> A-frags in registers; O = P @ V ; write O to X0 (wave-priv cols)
    #pragma unroll
    for (int n = 0; n < 2; ++n) {
      bf16x8 pa0 = redist(s[0][n], s[1][n], srcA, hi);   // keys  0..31
      bf16x8 pa1 = redist(s[2][n], s[3][n], srcA, hi);   // keys 32..63
      #pragma unroll
      for (int d = 0; d < 2; ++d) {
        f32x4 o = (f32x4){0.f, 0.f, 0.f, 0.f};
        o = mfma16(pa0, vb[d][0], o);
        o = mfma16(pa1, vb[d][1], o);
        #pragma unroll
        for (int r = 0; r < 4; ++r)
          X0[(p * 32 + n * 16 + q * 4 + r) * LDA + w * 32 + d * 16 + c] = (bf16)o[r];
      }
    }
  }
  __syncthreads();   // all O written before projection reads full rows

  // ---- stage 4: out = O @ Wp + bp ; wave w -> cols [32w,32w+32) ----
  {
    f32x4 acc[4][2];
    #pragma unroll
    for (int n = 0; n < 2; ++n) {
      float bv = bp[w * 32 + n * 16 + c];
      #pragma unroll
      for (int m = 0; m < 4; ++m) acc[m][n] = (f32x4){bv, bv, bv, bv};
    }
    #pragma unroll
    for (int kt = 0; kt < 8; ++kt) {
      bf16x8 af[4], bw[2];
      #pragma unroll
      for (int m = 0; m < 4; ++m)
        af[m] = *(const bf16x8*)(X0 + (m * 16 + c) * LDA + kt * 32 + q * 8);
      #pragma unroll
      for (int n = 0; n < 2; ++n)
        bw[n] = *(const bf16x8*)(WpT + (w * 32 + n * 16 + c) * 256 + kt * 32 + q * 8);
      #pragma unroll
      for (int m = 0; m < 4; ++m)
        #pragma unroll
        for (int n = 0; n < 2; ++n)
          acc[m][n] = mfma16(af[m], bw[n], acc[m][n]);
    }
    float* dst = out + xoff;
    #pragma unroll
    for (int m = 0; m < 4; ++m)
      #pragma unroll
      for (int n = 0; n < 2; ++n)
        #pragma unroll
        for (int r = 0; r < 4; ++r)
          dst[(m * 16 + q * 4 + r) * 256 + w * 32 + n * 16 + c] = acc[m][n][r];
  }
}

extern "C" void kernel_launch(void* const* d_in, const int* in_sizes, int n_in,
                              void* d_out, int out_size, void* d_ws, size_t ws_size,
                              hipStream_t stream) {
  const float* Xq   = (const float*)d_in[0];
  const float* Xs   = (const float*)d_in[1];
  const float* Wq   = (const float*)d_in[2];
  const float* bq   = (const float*)d_in[3];
  const float* Wkv  = (const float*)d_in[4];
  const float* bkv  = (const float*)d_in[5];
  const float* btab = (const float*)d_in[6];
  const float* Wp   = (const float*)d_in[7];
  const float* bp   = (const float*)d_in[8];
  float* out = (float*)d_out;

  char* ws = (char*)d_ws;
  bf16*  WqT   = (bf16*)(ws);                 // 256x256 bf16 = 131072 B
  bf16*  WkvT  = (bf16*)(ws + 131072);        // 512x256 bf16 = 262144 B
  bf16*  WpT   = (bf16*)(ws + 393216);        // 256x256 bf16 = 131072 B
  float* biasT = (float*)(ws + 524288);       // 8x64x64 f32  = 131072 B

  const int Bw = in_sizes[0] / (64 * 256);    // number of windows (4096)

  prep_kernel<<<dim3(576), dim3(512), 0, stream>>>(Wq, Wkv, Wp, btab,
                                                   WqT, WkvT, WpT, biasT);
  fused_kernel<<<dim3(Bw), dim3(512), 0, stream>>>(Xq, Xs, bq, bkv, bp,
                                                   WqT, WkvT, WpT, biasT, out);
}